// Round 3
// baseline (528.232 us; speedup 1.0000x reference)
//
#include <hip/hip_runtime.h>

#define BATCH   8
#define CDIM    32
#define KLBL    64
#define NCHUNK  8   // chunks per (b,c) row -> grid = 8*32*8 = 2048 blocks

// ---------------- Kernel 1: c-split segment sums ----------------
// grid = (NCHUNK, CDIM, BATCH), block = 256.
// Each block streams one contiguous chunk of pred[b][c][*] and accumulates
// s_sums[64] (one c). Labels are re-read per c from L2/L3 (6.4 MB resident).
template <bool C0>
__device__ __forceinline__ void seg_body(
    const int4* __restrict__ lp,     // label[b] as int4
    const float4* __restrict__ pp,   // pred[b][c] as float4
    int g0, int g1, float* s_sums, float* s_counts) {
  const int tid = threadIdx.x;
  const int cnt   = g1 - g0;
  const int nfull = cnt >> 8;        // full 256-wide tiles
  int idx = g0 + tid;

  int4 l;  float4 v;
  if (nfull > 0) { l = lp[idx]; v = pp[idx]; }

  for (int it = 0; it < nfull; ++it) {
    const int nidx = idx + 256;
    int4 ln; float4 vn;
    if (it + 1 < nfull) { ln = lp[nidx]; vn = pp[nidx]; }  // prefetch (uniform cond)

    atomicAdd(&s_sums[l.x], v.x);
    atomicAdd(&s_sums[l.y], v.y);
    atomicAdd(&s_sums[l.z], v.z);
    atomicAdd(&s_sums[l.w], v.w);
    if (C0) {
      atomicAdd(&s_counts[l.x], 1.f);
      atomicAdd(&s_counts[l.y], 1.f);
      atomicAdd(&s_counts[l.z], 1.f);
      atomicAdd(&s_counts[l.w], 1.f);
    }
    idx = nidx; l = ln; v = vn;
  }
  // tail groups (idx = g0 + nfull*256 + tid)
  if (idx < g1) {
    l = lp[idx]; v = pp[idx];
    atomicAdd(&s_sums[l.x], v.x);
    atomicAdd(&s_sums[l.y], v.y);
    atomicAdd(&s_sums[l.z], v.z);
    atomicAdd(&s_sums[l.w], v.w);
    if (C0) {
      atomicAdd(&s_counts[l.x], 1.f);
      atomicAdd(&s_counts[l.y], 1.f);
      atomicAdd(&s_counts[l.z], 1.f);
      atomicAdd(&s_counts[l.w], 1.f);
    }
  }
}

__global__ __launch_bounds__(256) void seg_sum_kernel(
    const float* __restrict__ pred,    // [B][C][N]
    const int*   __restrict__ label,   // [B][N]
    float* __restrict__ gsums,         // [B][K][C] (pre-zeroed)
    float* __restrict__ gcounts,       // [B][K]    (pre-zeroed)
    int N) {
  __shared__ float s_sums[KLBL];
  __shared__ float s_counts[KLBL];
  const int tid = threadIdx.x;
  const int chunk = blockIdx.x, c = blockIdx.y, b = blockIdx.z;

  if (tid < KLBL) { s_sums[tid] = 0.f; s_counts[tid] = 0.f; }
  __syncthreads();

  const int G = N >> 2;  // float4 groups per row
  const int g0 = (int)(((long long)chunk * G) / NCHUNK);
  const int g1 = (int)(((long long)(chunk + 1) * G) / NCHUNK);

  const int4*   lp = (const int4*)(label + (size_t)b * N);
  const float4* pp = (const float4*)(pred + ((size_t)b * CDIM + c) * N);

  if (c == 0) seg_body<true >(lp, pp, g0, g1, s_sums, s_counts);
  else        seg_body<false>(lp, pp, g0, g1, s_sums, s_counts);

  // scalar tail for N % 4 (last chunk only; empty when N % 4 == 0)
  if (chunk == NCHUNK - 1) {
    const int*   lb = label + (size_t)b * N;
    const float* pb = pred + ((size_t)b * CDIM + c) * N;
    for (int n = (G << 2) + tid; n < N; n += 256) {
      const int lab = lb[n];
      atomicAdd(&s_sums[lab], pb[n]);
      if (c == 0) atomicAdd(&s_counts[lab], 1.f);
    }
  }
  __syncthreads();

  if (tid < KLBL) {
    atomicAdd(&gsums[((size_t)b * KLBL + tid) * CDIM + c], s_sums[tid]);
    if (c == 0) atomicAdd(&gcounts[b * KLBL + tid], s_counts[tid]);
  }
}

// ---------------- Kernel 2: centers -> pairwise hinge loss ----------------
// grid = BATCH, block = 256
__global__ __launch_bounds__(256) void loss_kernel(
    const float* __restrict__ gsums,    // [B][K][C]
    const float* __restrict__ gcounts,  // [B][K]
    float* __restrict__ out) {          // scalar (pre-zeroed)
  const int b = blockIdx.x;
  __shared__ float s_center[KLBL * CDIM];  // [k][c]
  __shared__ float s_red[256];

  for (int i = threadIdx.x; i < KLBL * CDIM; i += 256) {
    const float cnt = fmaxf(gcounts[b * KLBL + (i >> 5)], 1.0f);
    s_center[i] = gsums[(size_t)b * KLBL * CDIM + i] / cnt;
  }
  __syncthreads();

  float acc = 0.f;
  for (int p = threadIdx.x; p < CDIM * CDIM; p += 256) {
    const int i = p >> 5, j = p & 31;
    float g = 0.f, ni = 0.f, nj = 0.f;
#pragma unroll
    for (int k = 0; k < KLBL; ++k) {
      const float ci = s_center[k * CDIM + i];
      const float cj = s_center[k * CDIM + j];
      g  += ci * cj;
      ni += ci * ci;
      nj += cj * cj;
    }
    float sq = fmaxf(ni + nj - 2.f * g, 0.f);
    const float dist = (sq > 0.f) ? sqrtf(sq) : 0.f;
    const float h = fmaxf(3.0f - dist, 0.f);  // 2*D_DIST = 3.0
    acc += h * h;
  }

  s_red[threadIdx.x] = acc;
  __syncthreads();
  for (int s = 128; s > 0; s >>= 1) {
    if (threadIdx.x < s) s_red[threadIdx.x] += s_red[threadIdx.x + s];
    __syncthreads();
  }
  if (threadIdx.x == 0)
    atomicAdd(out, s_red[0] / (2.0f * (float)KLBL * ((float)KLBL - 1.0f)));
}

// ---------------- launch ----------------
extern "C" void kernel_launch(void* const* d_in, const int* in_sizes, int n_in,
                              void* d_out, int out_size, void* d_ws, size_t ws_size,
                              hipStream_t stream) {
  const float* pred  = (const float*)d_in[0];
  const int*   label = (const int*)d_in[1];
  float* out = (float*)d_out;

  const int N = in_sizes[1] / BATCH;  // 200000

  float* gsums   = (float*)d_ws;                       // B*K*C
  float* gcounts = gsums + (size_t)BATCH * KLBL * CDIM; // B*K

  const size_t accum_bytes =
      (size_t)(BATCH * KLBL * CDIM + BATCH * KLBL) * sizeof(float);
  hipMemsetAsync(d_ws, 0, accum_bytes, stream);
  hipMemsetAsync(d_out, 0, sizeof(float), stream);

  dim3 grid1(NCHUNK, CDIM, BATCH);
  seg_sum_kernel<<<grid1, 256, 0, stream>>>(pred, label, gsums, gcounts, N);
  loss_kernel<<<BATCH, 256, 0, stream>>>(gsums, gcounts, out);
}

// Round 4
// 331.426 us; speedup vs baseline: 1.5938x; 1.5938x over previous
//
#include <hip/hip_runtime.h>
#include <stdint.h>

#define BATCH   8
#define CDIM    32
#define KLBL    64
#define NCHUNK  8
#define SEGF    256              // floats (or label bytes) per 1KB segment
#define TSEG    16               // segments per tile
#define TILEF   (TSEG * SEGF)    // 4096 floats = 16KB pred per tile
#define LABPAD  4096             // ws overread pad for label staging

// fire-and-forget global->LDS DMA, 16B per lane (64 lanes = 1KB per call).
// LDS dest = wave-uniform base + lane*16 (HW rule); global src is per-lane.
__device__ __forceinline__ void stage16(const void* g, void* l) {
  __builtin_amdgcn_global_load_lds(
      (const __attribute__((address_space(1))) void*)(uintptr_t)g,
      (__attribute__((address_space(3))) void*)(uintptr_t)l, 16, 0, 0);
}

// ---------------- Kernel 0: pack labels to u8 + count histogram ----------
// grid = (ceil(N/4/256), BATCH), block = 256. N % 4 == 0.
__global__ __launch_bounds__(256) void lab_prep_kernel(
    const int* __restrict__ lab, uint8_t* __restrict__ lab8,
    float* __restrict__ gcounts, int N) {
  __shared__ float s_cnt[KLBL];
  const int tid = threadIdx.x;
  const int b = blockIdx.y;
  if (tid < KLBL) s_cnt[tid] = 0.f;
  __syncthreads();

  const int W = N >> 2;
  const int i = blockIdx.x * 256 + tid;
  if (i < W) {
    const int4 l4 = ((const int4*)(lab + (size_t)b * N))[i];
    const uint32_t w = (uint32_t)(l4.x & 0xff) | ((uint32_t)(l4.y & 0xff) << 8) |
                       ((uint32_t)(l4.z & 0xff) << 16) | ((uint32_t)(l4.w & 0xff) << 24);
    ((uint32_t*)(lab8 + (size_t)b * N))[i] = w;
    atomicAdd(&s_cnt[l4.x], 1.f);
    atomicAdd(&s_cnt[l4.y], 1.f);
    atomicAdd(&s_cnt[l4.z], 1.f);
    atomicAdd(&s_cnt[l4.w], 1.f);
  }
  __syncthreads();
  if (tid < KLBL) atomicAdd(&gcounts[b * KLBL + tid], s_cnt[tid]);
}

// ---------------- Kernel 1: staged c-split segment sums ------------------
// grid = (NCHUNK, CDIM, BATCH), block = 256 (4 waves).
__global__ __launch_bounds__(256) void seg_sum_kernel(
    const float* __restrict__ pred,     // [B][C][N]
    const uint8_t* __restrict__ lab8,   // [B][N] (+pad)
    float* __restrict__ gsums,          // [B][K][C] pre-zeroed
    int N) {
  __shared__ float    s_pred[2 * TILEF];   // 32KB
  __shared__ uint32_t s_lab4[2 * 1024];    // 8KB (4096B per buffer)
  __shared__ float    s_sums[KLBL];

  const int tid  = threadIdx.x;
  const int wave = tid >> 6;
  const int lane = tid & 63;
  const int chunk = blockIdx.x, c = blockIdx.y, b = blockIdx.z;

  if (tid < KLBL) s_sums[tid] = 0.f;
  __syncthreads();

  const float*   prow = pred + ((size_t)b * CDIM + c) * N;
  const uint8_t* lrow = lab8 + (size_t)b * N;

  const int S  = N / SEGF;                  // full 1KB segments in the row
  const int T  = (S + TSEG - 1) / TSEG;     // tiles in the row
  const int t0 = chunk * T / NCHUNK;
  const int t1 = (chunk + 1) * T / NCHUNK;

  // ---- staging helper: pred (up to 16 segs, exact) + labels (always 4KB,
  //      ws padded so the ragged overread is in-bounds) ----
  auto stage_tile = [&](int t, int buf) {
    const int segBeg = t * TSEG;
    const int segEnd = min(segBeg + TSEG, S);
    float* lp = s_pred + buf * TILEF;
    for (int s = segBeg + wave; s < segEnd; s += 4)
      stage16(prow + (size_t)s * SEGF + lane * 4, lp + (s - segBeg) * SEGF);
    stage16(lrow + (size_t)segBeg * SEGF + wave * 1024 + lane * 16,
            (uint8_t*)(s_lab4 + buf * 1024) + wave * 1024);
  };

  auto process_tile = [&](int t, int buf) {
    const int segs = min(TSEG, S - t * TSEG);
    const int ngroups = segs * 64;          // float4 groups in tile
    const float4*   lp = (const float4*)(s_pred + buf * TILEF);
    const uint32_t* ll = s_lab4 + buf * 1024;
    for (int g = tid; g < ngroups; g += 256) {
      const float4  v = lp[g];
      const uint32_t w = ll[g];
      atomicAdd(&s_sums[w & 0xff], v.x);
      atomicAdd(&s_sums[(w >> 8) & 0xff], v.y);
      atomicAdd(&s_sums[(w >> 16) & 0xff], v.z);
      atomicAdd(&s_sums[w >> 24], v.w);
    }
  };

  if (t0 < t1) {
    stage_tile(t0, 0);
    for (int t = t0; t < t1; ++t) {
      const int cur = (t - t0) & 1;
      const bool have_next = (t + 1 < t1);
      bool next_full = false;
      if (have_next) {
        next_full = ((t + 1) * TSEG + TSEG <= S);
        stage_tile(t + 1, cur ^ 1);
      }
      // wait for CURRENT tile's 5 stages (next tile's stay in flight)
      if (have_next) {
        if (next_full) asm volatile("s_waitcnt vmcnt(5)" ::: "memory");
        else           asm volatile("s_waitcnt vmcnt(3)" ::: "memory");
      } else {
        asm volatile("s_waitcnt vmcnt(0)" ::: "memory");
      }
      __builtin_amdgcn_sched_barrier(0);
      __builtin_amdgcn_s_barrier();        // all waves' stages landed
      __builtin_amdgcn_sched_barrier(0);

      process_tile(t, cur);

      asm volatile("s_waitcnt lgkmcnt(0)" ::: "memory");  // my DS ops drained
      __builtin_amdgcn_sched_barrier(0);
      __builtin_amdgcn_s_barrier();        // buffer safe to re-stage
      __builtin_amdgcn_sched_barrier(0);
    }
  }

  // row remainder (N - S*256 < 256 elems), last chunk only
  if (t1 == T) {
    const int base = S * SEGF;
    const int r = N - base;
    if (tid < r) {
      const float v = prow[base + tid];
      const int k = lrow[base + tid];
      atomicAdd(&s_sums[k], v);
    }
  }

  __syncthreads();
  if (tid < KLBL)
    atomicAdd(&gsums[((size_t)b * KLBL + tid) * CDIM + c], s_sums[tid]);
}

// ---------------- Kernel 2: centers -> pairwise hinge loss ----------------
__global__ __launch_bounds__(256) void loss_kernel(
    const float* __restrict__ gsums,    // [B][K][C]
    const float* __restrict__ gcounts,  // [B][K]
    float* __restrict__ out) {          // scalar, pre-zeroed
  const int b = blockIdx.x;
  __shared__ float s_center[KLBL * CDIM];
  __shared__ float s_red[256];

  for (int i = threadIdx.x; i < KLBL * CDIM; i += 256) {
    const float cnt = fmaxf(gcounts[b * KLBL + (i >> 5)], 1.0f);
    s_center[i] = gsums[(size_t)b * KLBL * CDIM + i] / cnt;
  }
  __syncthreads();

  float acc = 0.f;
  for (int p = threadIdx.x; p < CDIM * CDIM; p += 256) {
    const int i = p >> 5, j = p & 31;
    float g = 0.f, ni = 0.f, nj = 0.f;
#pragma unroll
    for (int k = 0; k < KLBL; ++k) {
      const float ci = s_center[k * CDIM + i];
      const float cj = s_center[k * CDIM + j];
      g  += ci * cj;
      ni += ci * ci;
      nj += cj * cj;
    }
    float sq = fmaxf(ni + nj - 2.f * g, 0.f);
    const float dist = (sq > 0.f) ? sqrtf(sq) : 0.f;
    const float h = fmaxf(3.0f - dist, 0.f);   // 2*D_DIST = 3.0
    acc += h * h;
  }

  s_red[threadIdx.x] = acc;
  __syncthreads();
  for (int s = 128; s > 0; s >>= 1) {
    if (threadIdx.x < s) s_red[threadIdx.x] += s_red[threadIdx.x + s];
    __syncthreads();
  }
  if (threadIdx.x == 0)
    atomicAdd(out, s_red[0] / (2.0f * (float)KLBL * ((float)KLBL - 1.0f)));
}

// ---------------- launch ----------------
extern "C" void kernel_launch(void* const* d_in, const int* in_sizes, int n_in,
                              void* d_out, int out_size, void* d_ws, size_t ws_size,
                              hipStream_t stream) {
  const float* pred  = (const float*)d_in[0];
  const int*   label = (const int*)d_in[1];
  float* out = (float*)d_out;

  const int N = in_sizes[1] / BATCH;  // 200000

  // ws layout: gsums [B*K*C f32] | gcounts [B*K f32] | lab8 [B*N u8 + pad]
  float*   gsums   = (float*)d_ws;
  float*   gcounts = gsums + (size_t)BATCH * KLBL * CDIM;
  uint8_t* lab8    = (uint8_t*)(gcounts + BATCH * KLBL);

  const size_t accum_bytes =
      (size_t)(BATCH * KLBL * CDIM + BATCH * KLBL) * sizeof(float);
  hipMemsetAsync(d_ws, 0, accum_bytes, stream);
  hipMemsetAsync(d_out, 0, sizeof(float), stream);

  const int W = N >> 2;
  dim3 grid0((W + 255) / 256, BATCH);
  lab_prep_kernel<<<grid0, 256, 0, stream>>>(label, lab8, gcounts, N);

  dim3 grid1(NCHUNK, CDIM, BATCH);
  seg_sum_kernel<<<grid1, 256, 0, stream>>>(pred, lab8, gsums, N);

  loss_kernel<<<BATCH, 256, 0, stream>>>(gsums, gcounts, out);
}

// Round 5
// 68.435 us; speedup vs baseline: 7.7187x; 4.8429x over previous
//
#include <hip/hip_runtime.h>
#include <stdint.h>

#define BATCH    8
#define CDIM     32
#define KLBL     64
#define NPB      200000          // n per batch (multiple of 32)
#define SLABS_PB 6250            // 32-n slabs per batch
#define CHUNKS   128             // blocks per batch -> grid 1024
#define TSLAB    4               // slabs per LDS tile (128 n)
#define LROWB    272             // bytes per LDS tile row: 128*2B + 16B pad
#define TILEB    (32 * LROWB)    // 8704 B per tile buffer

typedef __attribute__((ext_vector_type(8))) short bf16x8;
typedef __attribute__((ext_vector_type(4))) float f32x4;

union ABits { uint32_t u[4]; bf16x8 v; };

__device__ __forceinline__ uint32_t cvtpk_bf16(float lo, float hi) {
  uint32_t r;
  asm volatile("v_cvt_pk_bf16_f32 %0, %1, %2" : "=v"(r) : "v"(lo), "v"(hi));
  return r;
}

// ---------------- Kernel 0: pack labels i32 -> u8 (pure streaming) --------
__global__ __launch_bounds__(256) void pack_kernel(
    const int* __restrict__ lab, uint8_t* __restrict__ lab8, int total4) {
  const int i = blockIdx.x * 256 + threadIdx.x;
  if (i < total4) {
    const int4 l4 = ((const int4*)lab)[i];
    ((uint32_t*)lab8)[i] = (uint32_t)(l4.x & 0xff) |
                           ((uint32_t)(l4.y & 0xff) << 8) |
                           ((uint32_t)(l4.z & 0xff) << 16) |
                           ((uint32_t)(l4.w & 0xff) << 24);
  }
}

// ---------------- Kernel 1: one-hot MFMA segment sums ---------------------
// grid = (CHUNKS, BATCH), block = 256 (4 waves). Wave w owns k-tile w (16
// labels). Per 32-n slab: A = onehot (built in regs), B = pred^T tile from
// LDS (bf16), 3 MFMAs (c-tile0, c-tile1, ones->counts).
__global__ __launch_bounds__(256) void seg_mfma_kernel(
    const float* __restrict__ pred,     // [B][C][N] f32
    const uint8_t* __restrict__ lab8,   // [B][N] u8
    float* __restrict__ gsums,          // [B][K][C] pre-zeroed
    float* __restrict__ gcounts) {      // [B][K]    pre-zeroed
  __shared__ __align__(8)  uint32_t s_lab[400];          // <=49 slabs * 32B
  __shared__ __align__(16) uint8_t  s_tile[2][TILEB];    // dbuf bf16 tiles

  const int tid = threadIdx.x;
  const int wv = tid >> 6;        // wave = k-tile
  const int ln = tid & 63;
  const int chunk = blockIdx.x, b = blockIdx.y;

  const int s0 = (int)((long long)chunk * SLABS_PB / CHUNKS);
  const int s1 = (int)((long long)(chunk + 1) * SLABS_PB / CHUNKS);
  const int nslab = s1 - s0;              // 48 or 49
  const int base_n = s0 * 32;

  // ---- one-time: stage this block's labels into LDS ----
  const uint32_t* lsrc = (const uint32_t*)(lab8 + (size_t)b * NPB + base_n);
  for (int i = tid; i < nslab * 8; i += 256) s_lab[i] = lsrc[i];

  // per-wave fixed staging rows: j=0..3 -> rows wv*8 + j*2 + (ln>>5)
  const float* rowp[4];
#pragma unroll
  for (int j = 0; j < 4; ++j) {
    const int c = wv * 8 + j * 2 + (ln >> 5);
    rowp[j] = pred + ((size_t)b * CDIM + c) * NPB;
  }
  const int lan4 = (ln & 31) * 4;   // f32 offset within 128-n tile

  ABits ones;
  ones.u[0] = ones.u[1] = ones.u[2] = ones.u[3] = 0x3F803F80u;

  f32x4 acc0 = {0.f, 0.f, 0.f, 0.f};
  f32x4 acc1 = {0.f, 0.f, 0.f, 0.f};
  f32x4 accc = {0.f, 0.f, 0.f, 0.f};

  const int ntile = (nslab + TSLAB - 1) / TSLAB;
  const uint32_t myrow = (uint32_t)((ln & 15) + (wv << 4));

  float4 r0, r1, r2, r3;

  auto issue_loads = [&](int t) {
    int en = base_n + t * 128 + lan4;
    en = min(en, NPB - 4);
    r0 = *(const float4*)(rowp[0] + en);
    r1 = *(const float4*)(rowp[1] + en);
    r2 = *(const float4*)(rowp[2] + en);
    r3 = *(const float4*)(rowp[3] + en);
  };

  auto cvt_write = [&](int buf) {
    uint8_t* tb = s_tile[buf];
    const int off = (ln & 31) * 8;
#pragma unroll
    for (int j = 0; j < 4; ++j) {
      const float4 r = (j == 0) ? r0 : (j == 1) ? r1 : (j == 2) ? r2 : r3;
      const int c = wv * 8 + j * 2 + (ln >> 5);
      uint2 w;
      w.x = cvtpk_bf16(r.x, r.y);
      w.y = cvtpk_bf16(r.z, r.w);
      *(uint2*)(tb + c * LROWB + off) = w;
    }
  };

  auto process = [&](int t, int buf) {
    const uint8_t* tb = s_tile[buf];
    const int ns = min(TSLAB, nslab - t * TSLAB);
    const int rb = (ln & 15) * LROWB + (ln >> 4) * 16;
    for (int ss = 0; ss < ns; ++ss) {
      const int sb = t * TSLAB + ss;
      const uint2 lw =
          *(const uint2*)((const uint8_t*)s_lab + sb * 32 + (ln >> 4) * 8);
      ABits a;
      a.u[0] = (((lw.x) & 0xffu) == myrow ? 0x3F80u : 0u) |
               (((lw.x >> 8) & 0xffu) == myrow ? 0x3F800000u : 0u);
      a.u[1] = (((lw.x >> 16) & 0xffu) == myrow ? 0x3F80u : 0u) |
               (((lw.x >> 24) & 0xffu) == myrow ? 0x3F800000u : 0u);
      a.u[2] = (((lw.y) & 0xffu) == myrow ? 0x3F80u : 0u) |
               (((lw.y >> 8) & 0xffu) == myrow ? 0x3F800000u : 0u);
      a.u[3] = (((lw.y >> 16) & 0xffu) == myrow ? 0x3F80u : 0u) |
               (((lw.y >> 24) & 0xffu) == myrow ? 0x3F800000u : 0u);
      const bf16x8 b0 = *(const bf16x8*)(tb + rb + ss * 64);
      const bf16x8 b1 = *(const bf16x8*)(tb + rb + ss * 64 + 16 * LROWB);
      acc0 = __builtin_amdgcn_mfma_f32_16x16x32_bf16(a.v, b0, acc0, 0, 0, 0);
      acc1 = __builtin_amdgcn_mfma_f32_16x16x32_bf16(a.v, b1, acc1, 0, 0, 0);
      accc = __builtin_amdgcn_mfma_f32_16x16x32_bf16(a.v, ones.v, accc, 0, 0, 0);
    }
  };

  // prologue: stage tile 0
  issue_loads(0);
  cvt_write(0);
  __syncthreads();   // also covers s_lab staging

  for (int t = 0; t < ntile; ++t) {
    const int buf = t & 1;
    const bool more = (t + 1 < ntile);
    if (more) issue_loads(t + 1);          // in flight during process
    __builtin_amdgcn_sched_barrier(0);     // don't sink loads into process
    process(t, buf);
    if (more) cvt_write(buf ^ 1);          // waits vmcnt at first cvt use
    __syncthreads();
  }

  // ---- flush: lane holds D[row=(ln>>4)*4+r][col=ln&15] of its k-tile ----
  const int krb = (wv << 4) + ((ln >> 4) << 2);
  const int col = ln & 15;
  float* gs = gsums + (size_t)b * KLBL * CDIM;
#pragma unroll
  for (int r = 0; r < 4; ++r) {
    atomicAdd(&gs[(krb + r) * CDIM + col], acc0[r]);
    atomicAdd(&gs[(krb + r) * CDIM + 16 + col], acc1[r]);
  }
  if (col == 0) {
#pragma unroll
    for (int r = 0; r < 4; ++r)
      atomicAdd(&gcounts[b * KLBL + krb + r], accc[r]);
  }
}

// ---------------- Kernel 2: centers -> pairwise hinge loss ----------------
__global__ __launch_bounds__(256) void loss_kernel(
    const float* __restrict__ gsums,    // [B][K][C]
    const float* __restrict__ gcounts,  // [B][K]
    float* __restrict__ out) {          // scalar, pre-zeroed
  const int b = blockIdx.x;
  __shared__ float s_center[KLBL * CDIM];
  __shared__ float s_red[256];

  for (int i = threadIdx.x; i < KLBL * CDIM; i += 256) {
    const float cnt = fmaxf(gcounts[b * KLBL + (i >> 5)], 1.0f);
    s_center[i] = gsums[(size_t)b * KLBL * CDIM + i] / cnt;
  }
  __syncthreads();

  float acc = 0.f;
  for (int p = threadIdx.x; p < CDIM * CDIM; p += 256) {
    const int i = p >> 5, j = p & 31;
    float g = 0.f, ni = 0.f, nj = 0.f;
#pragma unroll
    for (int k = 0; k < KLBL; ++k) {
      const float ci = s_center[k * CDIM + i];
      const float cj = s_center[k * CDIM + j];
      g += ci * cj;
      ni += ci * ci;
      nj += cj * cj;
    }
    float sq = fmaxf(ni + nj - 2.f * g, 0.f);
    const float dist = (sq > 0.f) ? sqrtf(sq) : 0.f;
    const float h = fmaxf(3.0f - dist, 0.f);   // 2*D_DIST = 3.0
    acc += h * h;
  }

  s_red[threadIdx.x] = acc;
  __syncthreads();
  for (int s = 128; s > 0; s >>= 1) {
    if (threadIdx.x < s) s_red[threadIdx.x] += s_red[threadIdx.x + s];
    __syncthreads();
  }
  if (threadIdx.x == 0)
    atomicAdd(out, s_red[0] / (2.0f * (float)KLBL * ((float)KLBL - 1.0f)));
}

// ---------------- launch ----------------
extern "C" void kernel_launch(void* const* d_in, const int* in_sizes, int n_in,
                              void* d_out, int out_size, void* d_ws, size_t ws_size,
                              hipStream_t stream) {
  const float* pred  = (const float*)d_in[0];
  const int*   label = (const int*)d_in[1];
  float* out = (float*)d_out;

  // ws: gsums [B*K*C] | gcounts [B*K] | lab8 [B*NPB u8]
  float*   gsums   = (float*)d_ws;
  float*   gcounts = gsums + (size_t)BATCH * KLBL * CDIM;
  uint8_t* lab8    = (uint8_t*)(gcounts + BATCH * KLBL);

  const size_t accum_bytes =
      (size_t)(BATCH * KLBL * CDIM + BATCH * KLBL) * sizeof(float);
  hipMemsetAsync(d_ws, 0, accum_bytes, stream);
  hipMemsetAsync(d_out, 0, sizeof(float), stream);

  const int total4 = BATCH * NPB / 4;   // 400000
  pack_kernel<<<(total4 + 255) / 256, 256, 0, stream>>>(label, lab8, total4);

  dim3 grid1(CHUNKS, BATCH);
  seg_mfma_kernel<<<grid1, 256, 0, stream>>>(pred, lab8, gsums, gcounts);

  loss_kernel<<<BATCH, 256, 0, stream>>>(gsums, gcounts, out);
}

// Round 6
// 66.327 us; speedup vs baseline: 7.9641x; 1.0318x over previous
//
#include <hip/hip_runtime.h>
#include <stdint.h>

#define BATCH    8
#define CDIM     32
#define KLBL     64
#define NPB      200000          // n per batch (multiple of 32)
#define SLABS_PB 6250            // 32-n slabs per batch
#define CHUNKS   128             // blocks per batch -> grid 1024
#define TSLAB    4               // slabs per LDS tile (128 n)
#define LROWB    272             // bytes per LDS tile row: 128*2B + 16B pad
#define TILEB    (32 * LROWB)    // 8704 B per tile buffer

typedef __attribute__((ext_vector_type(8))) short bf16x8;
typedef __attribute__((ext_vector_type(4))) float f32x4;

union ABits { uint32_t u[4]; bf16x8 v; };

__device__ __forceinline__ uint32_t cvtpk_bf16(float lo, float hi) {
  uint32_t r;
  asm volatile("v_cvt_pk_bf16_f32 %0, %1, %2" : "=v"(r) : "v"(lo), "v"(hi));
  return r;
}

// ---------------- Kernel 1: one-hot MFMA segment sums ---------------------
// grid = (CHUNKS, BATCH), block = 256 (4 waves). Wave w owns k-tile w (16
// labels). Per 32-n slab: A = onehot (built in regs from u8 labels), B =
// pred^T tile from LDS (bf16), 3 MFMAs (c-tile0, c-tile1, ones->counts).
// Depth-2 register prefetch: loads for tile t+2 issued at iter t.
__global__ __launch_bounds__(256) void seg_mfma_kernel(
    const float* __restrict__ pred,     // [B][C][N] f32
    const int*   __restrict__ label,    // [B][N] i32
    float* __restrict__ gsums,          // [B][K][C] pre-zeroed
    float* __restrict__ gcounts) {      // [B][K]    pre-zeroed
  __shared__ __align__(8)  uint32_t s_lab[400];          // <=49 slabs * 32B
  __shared__ __align__(16) uint8_t  s_tile[2][TILEB];    // dbuf bf16 tiles

  const int tid = threadIdx.x;
  const int wv = tid >> 6;        // wave = k-tile
  const int ln = tid & 63;
  const int chunk = blockIdx.x, b = blockIdx.y;

  const int s0 = (int)((long long)chunk * SLABS_PB / CHUNKS);
  const int s1 = (int)((long long)(chunk + 1) * SLABS_PB / CHUNKS);
  const int nslab = s1 - s0;              // 48 or 49
  const int base_n = s0 * 32;

  // ---- one-time: stage this block's labels (i32 -> packed u8) into LDS ----
  const int4* lsrc = (const int4*)(label + (size_t)b * NPB + base_n);
  for (int i = tid; i < nslab * 8; i += 256) {
    const int4 l4 = lsrc[i];
    s_lab[i] = (uint32_t)(l4.x & 0xff) | ((uint32_t)(l4.y & 0xff) << 8) |
               ((uint32_t)(l4.z & 0xff) << 16) | ((uint32_t)(l4.w & 0xff) << 24);
  }

  // per-wave fixed staging rows: j=0..3 -> channel wv*8 + j*2 + (ln>>5)
  const float* rowp[4];
#pragma unroll
  for (int j = 0; j < 4; ++j) {
    const int c = wv * 8 + j * 2 + (ln >> 5);
    rowp[j] = pred + ((size_t)b * CDIM + c) * NPB;
  }
  const int lan4 = (ln & 31) * 4;   // f32 offset within 128-n tile

  ABits ones;
  ones.u[0] = ones.u[1] = ones.u[2] = ones.u[3] = 0x3F803F80u;

  f32x4 acc0 = {0.f, 0.f, 0.f, 0.f};
  f32x4 acc1 = {0.f, 0.f, 0.f, 0.f};
  f32x4 accc = {0.f, 0.f, 0.f, 0.f};

  const int ntile = (nslab + TSLAB - 1) / TSLAB;
  const uint32_t myrow = (uint32_t)((ln & 15) + (wv << 4));

  // two named prefetch register sets (static indexing only)
  float4 rA0, rA1, rA2, rA3;   // even tiles
  float4 rB0, rB1, rB2, rB3;   // odd tiles

  auto loadA = [&](int t) {
    const int en = min(base_n + t * 128 + lan4, NPB - 4);
    rA0 = *(const float4*)(rowp[0] + en);
    rA1 = *(const float4*)(rowp[1] + en);
    rA2 = *(const float4*)(rowp[2] + en);
    rA3 = *(const float4*)(rowp[3] + en);
  };
  auto loadB = [&](int t) {
    const int en = min(base_n + t * 128 + lan4, NPB - 4);
    rB0 = *(const float4*)(rowp[0] + en);
    rB1 = *(const float4*)(rowp[1] + en);
    rB2 = *(const float4*)(rowp[2] + en);
    rB3 = *(const float4*)(rowp[3] + en);
  };

  const int cvt_off = (ln & 31) * 8;
  auto cvtA = [&](int buf) {
    uint8_t* tb = s_tile[buf];
#pragma unroll
    for (int j = 0; j < 4; ++j) {
      const float4 r = (j == 0) ? rA0 : (j == 1) ? rA1 : (j == 2) ? rA2 : rA3;
      const int c = wv * 8 + j * 2 + (ln >> 5);
      uint2 w;
      w.x = cvtpk_bf16(r.x, r.y);
      w.y = cvtpk_bf16(r.z, r.w);
      *(uint2*)(tb + c * LROWB + cvt_off) = w;
    }
  };
  auto cvtB = [&](int buf) {
    uint8_t* tb = s_tile[buf];
#pragma unroll
    for (int j = 0; j < 4; ++j) {
      const float4 r = (j == 0) ? rB0 : (j == 1) ? rB1 : (j == 2) ? rB2 : rB3;
      const int c = wv * 8 + j * 2 + (ln >> 5);
      uint2 w;
      w.x = cvtpk_bf16(r.x, r.y);
      w.y = cvtpk_bf16(r.z, r.w);
      *(uint2*)(tb + c * LROWB + cvt_off) = w;
    }
  };

  auto process = [&](int t, int buf) {
    const uint8_t* tb = s_tile[buf];
    const int ns = min(TSLAB, nslab - t * TSLAB);
    const int rb = (ln & 15) * LROWB + (ln >> 4) * 16;
    for (int ss = 0; ss < ns; ++ss) {
      const int sb = t * TSLAB + ss;
      const uint2 lw =
          *(const uint2*)((const uint8_t*)s_lab + sb * 32 + (ln >> 4) * 8);
      ABits a;
      a.u[0] = (((lw.x) & 0xffu) == myrow ? 0x3F80u : 0u) |
               (((lw.x >> 8) & 0xffu) == myrow ? 0x3F800000u : 0u);
      a.u[1] = (((lw.x >> 16) & 0xffu) == myrow ? 0x3F80u : 0u) |
               (((lw.x >> 24) & 0xffu) == myrow ? 0x3F800000u : 0u);
      a.u[2] = (((lw.y) & 0xffu) == myrow ? 0x3F80u : 0u) |
               (((lw.y >> 8) & 0xffu) == myrow ? 0x3F800000u : 0u);
      a.u[3] = (((lw.y >> 16) & 0xffu) == myrow ? 0x3F80u : 0u) |
               (((lw.y >> 24) & 0xffu) == myrow ? 0x3F800000u : 0u);
      const bf16x8 b0 = *(const bf16x8*)(tb + rb + ss * 64);
      const bf16x8 b1 = *(const bf16x8*)(tb + rb + ss * 64 + 16 * LROWB);
      acc0 = __builtin_amdgcn_mfma_f32_16x16x32_bf16(a.v, b0, acc0, 0, 0, 0);
      acc1 = __builtin_amdgcn_mfma_f32_16x16x32_bf16(a.v, b1, acc1, 0, 0, 0);
      accc = __builtin_amdgcn_mfma_f32_16x16x32_bf16(a.v, ones.v, accc, 0, 0, 0);
    }
  };

  // ---- prologue: tile0 staged (latency exposed once), tile1 in flight ----
  loadA(0);
  if (ntile > 1) loadB(1);
  cvtA(0);             // implicit waitcnt on rA*
  __syncthreads();     // also covers s_lab staging

  // ---- main loop, unrolled x2 for static reg-set selection ----
  int t = 0;
  while (t < ntile) {
    // even iteration: process tile t from buf0
    if (t + 2 < ntile) loadA(t + 2);
    __builtin_amdgcn_sched_barrier(0);   // keep loads above process
    process(t, 0);
    if (t + 1 < ntile) cvtB(1);          // consumes set issued 2 iters back
    __syncthreads();
    ++t;
    if (t >= ntile) break;
    // odd iteration: process tile t from buf1
    if (t + 2 < ntile) loadB(t + 2);
    __builtin_amdgcn_sched_barrier(0);
    process(t, 1);
    if (t + 1 < ntile) cvtA(0);
    __syncthreads();
    ++t;
  }

  // ---- flush: lane holds D[row=(ln>>4)*4+r][col=ln&15] of its k-tile ----
  const int krb = (wv << 4) + ((ln >> 4) << 2);
  const int col = ln & 15;
  float* gs = gsums + (size_t)b * KLBL * CDIM;
#pragma unroll
  for (int r = 0; r < 4; ++r) {
    atomicAdd(&gs[(krb + r) * CDIM + col], acc0[r]);
    atomicAdd(&gs[(krb + r) * CDIM + 16 + col], acc1[r]);
  }
  if (col == 0) {
#pragma unroll
    for (int r = 0; r < 4; ++r)
      atomicAdd(&gcounts[b * KLBL + krb + r], accc[r]);
  }
}

// ---------------- Kernel 2: centers -> pairwise hinge loss ----------------
__global__ __launch_bounds__(256) void loss_kernel(
    const float* __restrict__ gsums,    // [B][K][C]
    const float* __restrict__ gcounts,  // [B][K]
    float* __restrict__ out) {          // scalar, pre-zeroed
  const int b = blockIdx.x;
  __shared__ float s_center[KLBL * CDIM];
  __shared__ float s_red[256];

  for (int i = threadIdx.x; i < KLBL * CDIM; i += 256) {
    const float cnt = fmaxf(gcounts[b * KLBL + (i >> 5)], 1.0f);
    s_center[i] = gsums[(size_t)b * KLBL * CDIM + i] / cnt;
  }
  __syncthreads();

  float acc = 0.f;
  for (int p = threadIdx.x; p < CDIM * CDIM; p += 256) {
    const int i = p >> 5, j = p & 31;
    float g = 0.f, ni = 0.f, nj = 0.f;
#pragma unroll
    for (int k = 0; k < KLBL; ++k) {
      const float ci = s_center[k * CDIM + i];
      const float cj = s_center[k * CDIM + j];
      g += ci * cj;
      ni += ci * ci;
      nj += cj * cj;
    }
    float sq = fmaxf(ni + nj - 2.f * g, 0.f);
    const float dist = (sq > 0.f) ? sqrtf(sq) : 0.f;
    const float h = fmaxf(3.0f - dist, 0.f);   // 2*D_DIST = 3.0
    acc += h * h;
  }

  s_red[threadIdx.x] = acc;
  __syncthreads();
  for (int s = 128; s > 0; s >>= 1) {
    if (threadIdx.x < s) s_red[threadIdx.x] += s_red[threadIdx.x + s];
    __syncthreads();
  }
  if (threadIdx.x == 0)
    atomicAdd(out, s_red[0] / (2.0f * (float)KLBL * ((float)KLBL - 1.0f)));
}

// ---------------- launch ----------------
extern "C" void kernel_launch(void* const* d_in, const int* in_sizes, int n_in,
                              void* d_out, int out_size, void* d_ws, size_t ws_size,
                              hipStream_t stream) {
  const float* pred  = (const float*)d_in[0];
  const int*   label = (const int*)d_in[1];
  float* out = (float*)d_out;

  // ws: gsums [B*K*C] | gcounts [B*K]
  float* gsums   = (float*)d_ws;
  float* gcounts = gsums + (size_t)BATCH * KLBL * CDIM;

  const size_t accum_bytes =
      (size_t)(BATCH * KLBL * CDIM + BATCH * KLBL) * sizeof(float);
  hipMemsetAsync(d_ws, 0, accum_bytes, stream);
  hipMemsetAsync(d_out, 0, sizeof(float), stream);

  dim3 grid1(CHUNKS, BATCH);
  seg_mfma_kernel<<<grid1, 256, 0, stream>>>(pred, label, gsums, gcounts);

  loss_kernel<<<BATCH, 256, 0, stream>>>(gsums, gcounts, out);
}

// Round 7
// 65.391 us; speedup vs baseline: 8.0781x; 1.0143x over previous
//
#include <hip/hip_runtime.h>
#include <stdint.h>

#define BATCH    8
#define CDIM     32
#define KLBL     64
#define NPB      200000          // n per batch (200000 = 6250 * 32 exactly)
#define SLABS_PB 6250            // 32-n slabs per batch
#define CHUNKS   96              // blocks per batch -> grid 768 (3/CU at 4 w/SIMD)

typedef __attribute__((ext_vector_type(8))) short bf16x8;
typedef __attribute__((ext_vector_type(4))) float f32x4;

union ABits { uint32_t u[4]; bf16x8 v; };

__device__ __forceinline__ uint32_t cvtpk_bf16(float lo, float hi) {
  uint32_t r;
  asm volatile("v_cvt_pk_bf16_f32 %0, %1, %2" : "=v"(r) : "v"(lo), "v"(hi));
  return r;
}

// ---------------- Kernel 1: barrier-free one-hot MFMA segment sums --------
// grid = (CHUNKS, BATCH), block = 256 (4 waves). Each WAVE owns an exclusive
// n-range and computes the full 64k x 32c partial via 12 MFMA per 32-n slab
// (4 k-tiles x {c-lo, c-hi, ones->counts}). B-fragment loaded straight from
// global (lane ln&15 = channel row, 8 consecutive n at (ln>>4)*8) + cvt_pk.
// No LDS staging, no barriers in the loop -> loads pipeline freely.
__global__ __launch_bounds__(256) void seg_mfma_kernel(
    const float* __restrict__ pred,     // [B][C][N] f32
    const int*   __restrict__ label,    // [B][N] i32
    float* __restrict__ gsums,          // [B][K][C] pre-zeroed
    float* __restrict__ gcounts) {      // [B][K]    pre-zeroed
  __shared__ float s_part[4][KLBL * CDIM + KLBL];   // 33KB flush buffer

  const int tid = threadIdx.x;
  const int wv = tid >> 6;
  const int ln = tid & 63;
  const int chunk = blockIdx.x, b = blockIdx.y;

  const int s0 = (int)((long long)chunk * SLABS_PB / CHUNKS);
  const int s1 = (int)((long long)(chunk + 1) * SLABS_PB / CHUNKS);
  const int w0 = s0 + (int)((long long)(s1 - s0) * wv / 4);
  const int w1 = s0 + (int)((long long)(s1 - s0) * (wv + 1) / 4);

  const int crow = ln & 15;          // channel row (and A label-row)
  const int kseg = (ln >> 4) * 8;    // n sub-offset within slab

  const float* row0 = pred + ((size_t)b * CDIM + crow) * NPB;       // c-lo
  const float* row1 = pred + ((size_t)b * CDIM + crow + 16) * NPB;  // c-hi
  const int*   labp = label + (size_t)b * NPB;

  ABits ones;
  ones.u[0] = ones.u[1] = ones.u[2] = ones.u[3] = 0x3F803F80u;

  f32x4 acc[4][2];   // [k-tile][c-tile], all indices compile-time (unrolled)
  f32x4 accc[4];     // counts per k-tile
#pragma unroll
  for (int kt = 0; kt < 4; ++kt) {
    acc[kt][0] = (f32x4){0.f, 0.f, 0.f, 0.f};
    acc[kt][1] = (f32x4){0.f, 0.f, 0.f, 0.f};
    accc[kt]   = (f32x4){0.f, 0.f, 0.f, 0.f};
  }

  // two named prefetch register sets (depth-2, static names only)
  float4 fA0, fA1, fA2, fA3;  int4 lA0, lA1;   // even slabs
  float4 fB0, fB1, fB2, fB3;  int4 lB0, lB1;   // odd slabs

  auto loadA = [&](int s) {
    const int n0 = s * 32 + kseg;
    fA0 = *(const float4*)(row0 + n0);
    fA1 = *(const float4*)(row0 + n0 + 4);
    fA2 = *(const float4*)(row1 + n0);
    fA3 = *(const float4*)(row1 + n0 + 4);
    lA0 = *(const int4*)(labp + n0);
    lA1 = *(const int4*)(labp + n0 + 4);
  };
  auto loadB = [&](int s) {
    const int n0 = s * 32 + kseg;
    fB0 = *(const float4*)(row0 + n0);
    fB1 = *(const float4*)(row0 + n0 + 4);
    fB2 = *(const float4*)(row1 + n0);
    fB3 = *(const float4*)(row1 + n0 + 4);
    lB0 = *(const int4*)(labp + n0);
    lB1 = *(const int4*)(labp + n0 + 4);
  };

  ABits b0v, b1v, av[4];   // derived per slab (av indexed only by unrolled kt)

  auto derive = [&](const float4& f0, const float4& f1, const float4& f2,
                    const float4& f3, const int4& l0, const int4& l1) {
    b0v.u[0] = cvtpk_bf16(f0.x, f0.y);
    b0v.u[1] = cvtpk_bf16(f0.z, f0.w);
    b0v.u[2] = cvtpk_bf16(f1.x, f1.y);
    b0v.u[3] = cvtpk_bf16(f1.z, f1.w);
    b1v.u[0] = cvtpk_bf16(f2.x, f2.y);
    b1v.u[1] = cvtpk_bf16(f2.z, f2.w);
    b1v.u[2] = cvtpk_bf16(f3.x, f3.y);
    b1v.u[3] = cvtpk_bf16(f3.z, f3.w);
#pragma unroll
    for (int kt = 0; kt < 4; ++kt) {
      const int tgt = kt * 16 + crow;
      av[kt].u[0] = (l0.x == tgt ? 0x3F80u : 0u) | (l0.y == tgt ? 0x3F800000u : 0u);
      av[kt].u[1] = (l0.z == tgt ? 0x3F80u : 0u) | (l0.w == tgt ? 0x3F800000u : 0u);
      av[kt].u[2] = (l1.x == tgt ? 0x3F80u : 0u) | (l1.y == tgt ? 0x3F800000u : 0u);
      av[kt].u[3] = (l1.z == tgt ? 0x3F80u : 0u) | (l1.w == tgt ? 0x3F800000u : 0u);
    }
  };

  auto mfma_step = [&]() {
#pragma unroll
    for (int kt = 0; kt < 4; ++kt) {
      acc[kt][0] = __builtin_amdgcn_mfma_f32_16x16x32_bf16(av[kt].v, b0v.v, acc[kt][0], 0, 0, 0);
      acc[kt][1] = __builtin_amdgcn_mfma_f32_16x16x32_bf16(av[kt].v, b1v.v, acc[kt][1], 0, 0, 0);
      accc[kt]   = __builtin_amdgcn_mfma_f32_16x16x32_bf16(av[kt].v, ones.v, accc[kt], 0, 0, 0);
    }
  };

  // ---- prologue ----
  if (w0 < w1) loadA(w0);
  if (w0 + 1 < w1) loadB(w0 + 1);

  // ---- main loop: no barriers, loads for s+2 issued while s computes ----
  int s = w0;
  while (s < w1) {
    derive(fA0, fA1, fA2, fA3, lA0, lA1);    // waits only its own vmcnt slice
    if (s + 2 < w1) loadA(s + 2);
    __builtin_amdgcn_sched_barrier(0);       // keep loads above the MFMAs
    mfma_step();
    ++s;
    if (s >= w1) break;
    derive(fB0, fB1, fB2, fB3, lB0, lB1);
    if (s + 2 < w1) loadB(s + 2);
    __builtin_amdgcn_sched_barrier(0);
    mfma_step();
    ++s;
  }

  // ---- flush: block LDS reduce (4 waves), then 2112 global atomics ----
  // D mapping (m89-verified): col = ln&15, row = (ln>>4)*4 + r
#pragma unroll
  for (int kt = 0; kt < 4; ++kt) {
#pragma unroll
    for (int r = 0; r < 4; ++r) {
      const int k = kt * 16 + (ln >> 4) * 4 + r;
      s_part[wv][k * CDIM + crow]      = acc[kt][0][r];
      s_part[wv][k * CDIM + 16 + crow] = acc[kt][1][r];
      if (crow == 0) s_part[wv][KLBL * CDIM + k] = accc[kt][r];
    }
  }
  __syncthreads();

  float* gs = gsums + (size_t)b * KLBL * CDIM;
  for (int i = tid; i < KLBL * CDIM + KLBL; i += 256) {
    const float v = s_part[0][i] + s_part[1][i] + s_part[2][i] + s_part[3][i];
    if (i < KLBL * CDIM) atomicAdd(&gs[i], v);
    else                 atomicAdd(&gcounts[b * KLBL + (i - KLBL * CDIM)], v);
  }
}

// ---------------- Kernel 2: centers -> pairwise hinge loss ----------------
__global__ __launch_bounds__(256) void loss_kernel(
    const float* __restrict__ gsums,    // [B][K][C]
    const float* __restrict__ gcounts,  // [B][K]
    float* __restrict__ out) {          // scalar, pre-zeroed
  const int b = blockIdx.x;
  __shared__ float s_center[KLBL * CDIM];
  __shared__ float s_red[256];

  for (int i = threadIdx.x; i < KLBL * CDIM; i += 256) {
    const float cnt = fmaxf(gcounts[b * KLBL + (i >> 5)], 1.0f);
    s_center[i] = gsums[(size_t)b * KLBL * CDIM + i] / cnt;
  }
  __syncthreads();

  float acc = 0.f;
  for (int p = threadIdx.x; p < CDIM * CDIM; p += 256) {
    const int i = p >> 5, j = p & 31;
    float g = 0.f, ni = 0.f, nj = 0.f;
#pragma unroll
    for (int k = 0; k < KLBL; ++k) {
      const float ci = s_center[k * CDIM + i];
      const float cj = s_center[k * CDIM + j];
      g += ci * cj;
      ni += ci * ci;
      nj += cj * cj;
    }
    float sq = fmaxf(ni + nj - 2.f * g, 0.f);
    const float dist = (sq > 0.f) ? sqrtf(sq) : 0.f;
    const float h = fmaxf(3.0f - dist, 0.f);   // 2*D_DIST = 3.0
    acc += h * h;
  }

  s_red[threadIdx.x] = acc;
  __syncthreads();
  for (int s = 128; s > 0; s >>= 1) {
    if (threadIdx.x < s) s_red[threadIdx.x] += s_red[threadIdx.x + s];
    __syncthreads();
  }
  if (threadIdx.x == 0)
    atomicAdd(out, s_red[0] / (2.0f * (float)KLBL * ((float)KLBL - 1.0f)));
}

// ---------------- launch ----------------
extern "C" void kernel_launch(void* const* d_in, const int* in_sizes, int n_in,
                              void* d_out, int out_size, void* d_ws, size_t ws_size,
                              hipStream_t stream) {
  const float* pred  = (const float*)d_in[0];
  const int*   label = (const int*)d_in[1];
  float* out = (float*)d_out;

  // ws: gsums [B*K*C] | gcounts [B*K]
  float* gsums   = (float*)d_ws;
  float* gcounts = gsums + (size_t)BATCH * KLBL * CDIM;

  const size_t accum_bytes =
      (size_t)(BATCH * KLBL * CDIM + BATCH * KLBL) * sizeof(float);
  hipMemsetAsync(d_ws, 0, accum_bytes, stream);
  hipMemsetAsync(d_out, 0, sizeof(float), stream);

  dim3 grid1(CHUNKS, BATCH);
  seg_mfma_kernel<<<grid1, 256, 0, stream>>>(pred, label, gsums, gcounts);

  loss_kernel<<<BATCH, 256, 0, stream>>>(gsums, gcounts, out);
}